// Round 17
// baseline (640.232 us; speedup 1.0000x reference)
//
#include <hip/hip_runtime.h>
#include <hip/hip_bf16.h>
#include <cstdint>

#define N_NODES 100000
#define N_EDGES 800000
#define N_GRAPHS 64
#define POOL_SPLIT 16

typedef short short8 __attribute__((ext_vector_type(8)));
typedef float f32x4 __attribute__((ext_vector_type(4)));

__device__ __forceinline__ float leakyf(float x){ return x >= 0.0f ? x : 0.2f*x; }
__device__ __forceinline__ float reluf(float x){ return x > 0.0f ? x : 0.0f; }

__device__ __forceinline__ float bf2f(unsigned short u){
  union { uint32_t i; float f; } c; c.i = ((uint32_t)u) << 16; return c.f;
}
__device__ __forceinline__ unsigned short f2bf(float x){
  union { float f; uint32_t i; } c; c.f = x;
  uint32_t r = c.i + 0x7FFFu + ((c.i >> 16) & 1u);   // RNE
  return (unsigned short)(r >> 16);
}
__device__ __forceinline__ uint32_t pack2(float a, float b){
  return (uint32_t)f2bf(a) | ((uint32_t)f2bf(b) << 16);
}

// ================= CSR build =================
__global__ void zero_deg_kernel(int* __restrict__ deg, int n){
  int v = blockIdx.x*256 + threadIdx.x;
  if (v < n) deg[v] = 0;
}
__global__ void count_kernel(const int* __restrict__ dst, int* __restrict__ deg,
                             int* __restrict__ pos, int E){
  int e = blockIdx.x*256 + threadIdx.x;
  if (e < E) pos[e] = atomicAdd(&deg[dst[e]], 1);
}
__global__ __launch_bounds__(256) void scan1_kernel(const int* __restrict__ deg,
    int* __restrict__ rowptr, int* __restrict__ bsum, int n){
  __shared__ int sm[256];
  int t = threadIdx.x, i = blockIdx.x*256 + t;
  int v = (i < n) ? deg[i] : 0;
  sm[t] = v; __syncthreads();
  for (int off = 1; off < 256; off <<= 1){
    int x = (t >= off) ? sm[t-off] : 0;
    __syncthreads();
    sm[t] += x;
    __syncthreads();
  }
  if (i < n) rowptr[i] = sm[t] - v;
  if (t == 255) bsum[blockIdx.x] = sm[255];
}
__global__ __launch_bounds__(512) void scan2_kernel(int* __restrict__ bsum, int nb){
  __shared__ int sm[512];
  int t = threadIdx.x;
  int v = (t < nb) ? bsum[t] : 0;
  sm[t] = v; __syncthreads();
  for (int off = 1; off < 512; off <<= 1){
    int x = (t >= off) ? sm[t-off] : 0;
    __syncthreads();
    sm[t] += x;
    __syncthreads();
  }
  if (t < nb) bsum[t] = sm[t] - v;
}
__global__ void scan3_kernel(int* __restrict__ rowptr, const int* __restrict__ bsum, int n){
  int i = blockIdx.x*256 + threadIdx.x;
  if (i < n) rowptr[i] += bsum[blockIdx.x];
}
__global__ void scatter_kernel(const int* __restrict__ src, const int* __restrict__ dst,
                               const int* __restrict__ rowptr, const int* __restrict__ pos,
                               int* __restrict__ csr, int E){
  int e = blockIdx.x*256 + threadIdx.x;
  if (e < E) csr[rowptr[dst[e]] + pos[e]] = src[e];
}

// ================= all Wa = W @ a in one launch =================
// wa layout: [0:64) s1 | [64:128) d1 | [128:384) s2 | [384:640) d2 | [640:768) s3 | [768:896) d3
__global__ __launch_bounds__(256) void wa_all_kernel(
    const float* __restrict__ W1, const float* __restrict__ as1, const float* __restrict__ ad1,
    const float* __restrict__ W2, const float* __restrict__ as2, const float* __restrict__ ad2,
    const float* __restrict__ W3, const float* __restrict__ as3, const float* __restrict__ ad3,
    float* __restrict__ wa){
  int t = threadIdx.x;
  { float ss=0.f, dd=0.f; const float* wr = W2 + (size_t)t*128;
    for (int o=0;o<128;++o){ float w=wr[o]; ss+=w*as2[o]; dd+=w*ad2[o]; }
    wa[128+t]=ss; wa[384+t]=dd; }
  if (t < 128){ float ss=0.f, dd=0.f; const float* wr = W3 + (size_t)t*128;
    for (int o=0;o<128;++o){ float w=wr[o]; ss+=w*as3[o]; dd+=w*ad3[o]; }
    wa[640+t]=ss; wa[768+t]=dd; }
  if (t < 64){ float ss=0.f, dd=0.f;
    if (t < 59){ const float* wr = W1 + (size_t)t*256;
      for (int o=0;o<256;++o){ float w=wr[o]; ss+=w*as1[o]; dd+=w*ad1[o]; } }
    wa[t]=ss; wa[64+t]=dd; }
}

// ================= x -> bf16 [N,64] + layer-1 scores (fused) =================
__global__ __launch_bounds__(256) void x2bf_sd_kernel(const float* __restrict__ x,
    const float* __restrict__ wa_s, const float* __restrict__ wa_d,
    uint32_t* __restrict__ xb, float* __restrict__ s, float* __restrict__ d, int n){
  int hl = threadIdx.x & 31;
  int v = blockIdx.x*8 + (threadIdx.x >> 5);
  if (v >= n) return;
  int c0 = 2*hl, c1 = 2*hl + 1;
  float f0 = (c0 < 59) ? x[(size_t)v*59 + c0] : 0.f;
  float f1 = (c1 < 59) ? x[(size_t)v*59 + c1] : 0.f;
  xb[(size_t)v*32 + hl] = pack2(f0, f1);
  float ss = f0*wa_s[c0] + f1*wa_s[c1];
  float dd = f0*wa_d[c0] + f1*wa_d[c1];
  #pragma unroll
  for (int off = 16; off; off >>= 1){ ss += __shfl_xor(ss, off); dd += __shfl_xor(dd, off); }
  if (hl == 0){ s[v] = ss; d[v] = dd; }
}

// ================= per-node scores (bf16 input, K even) =================
__global__ __launch_bounds__(256) void sd_bf16_kernel(const unsigned short* __restrict__ in,
    const float* __restrict__ wa_s, const float* __restrict__ wa_d,
    float* __restrict__ s, float* __restrict__ d, int n, int K){
  int wid = threadIdx.x >> 6, lane = threadIdx.x & 63;
  int v = (blockIdx.x << 2) + wid;
  if (v >= n) return;
  float ss = 0.f, dd = 0.f;
  const unsigned short* row = in + (size_t)v*K;
  for (int k = lane*2; k < K; k += 128){
    uint32_t u = *(const uint32_t*)&row[k];
    float x0 = bf2f((unsigned short)(u & 0xFFFFu));
    float x1 = bf2f((unsigned short)(u >> 16));
    ss += x0*wa_s[k] + x1*wa_s[k+1];
    dd += x0*wa_d[k] + x1*wa_d[k+1];
  }
  for (int off = 32; off; off >>= 1){ ss += __shfl_down(ss, off); dd += __shfl_down(dd, off); }
  if (lane == 0){ s[v] = ss; d[v] = dd; }
}

// ================= half-wave edge-softmax aggregation (bf16 in/out) =================
template<int NC>
__device__ __forceinline__ void gload(const unsigned short* rowp, int hl, float* f){
  if constexpr (NC == 1){
    uint32_t u = ((const uint32_t*)rowp)[hl];
    f[0] = bf2f((unsigned short)(u & 0xFFFFu));
    f[1] = bf2f((unsigned short)(u >> 16));
  } else {
    uint2 u = ((const uint2*)rowp)[hl];
    f[0] = bf2f((unsigned short)(u.x & 0xFFFFu));
    f[1] = bf2f((unsigned short)(u.x >> 16));
    f[2] = bf2f((unsigned short)(u.y & 0xFFFFu));
    f[3] = bf2f((unsigned short)(u.y >> 16));
  }
}

// BR: bias+relu epilogue. SDF: fuse next-layer score computation.
// 8 nodes per 256-thread block; each half-wave (32 lanes) owns one dst node.
// 8-wide gather unroll for memory-level parallelism (latency-bound per r16 counters).
template<int NC, int BR, int SDF>
__global__ __launch_bounds__(256) void agg_half(
    const unsigned short* __restrict__ hb, const float* __restrict__ s,
    const float* __restrict__ dsc, const int* __restrict__ rowptr,
    const int* __restrict__ deg, const int* __restrict__ csr, float* __restrict__ ew,
    const float* __restrict__ bias,
    const float* __restrict__ sdw_s, const float* __restrict__ sdw_d,
    float* __restrict__ s_out, float* __restrict__ d_out,
    unsigned short* __restrict__ outp, int n){
  const int C  = NC*64;
  const int CH = NC*2;                    // channels per lane
  const int tid  = threadIdx.x;
  const int hl   = tid & 31;
  const int base = tid & 32;              // half-wave base lane within wave
  const int v = blockIdx.x*8 + (tid >> 5);
  if (v >= n) return;
  const int beg = rowptr[v], dg = deg[v];
  const float dv = dsc[v];
  const float e0 = leakyf(s[v] + dv);
  float acc[CH];

  if (dg <= 32){
    int srcl = 0; float sc = -1e30f;
    if (hl < dg){ srcl = csr[beg + hl]; sc = leakyf(s[srcl] + dv); }
    float mm = sc;
    #pragma unroll
    for (int off = 16; off; off >>= 1) mm = fmaxf(mm, __shfl_xor(mm, off));
    const float m = fmaxf(e0, mm);
    float w = (hl < dg) ? __expf(sc - m) : 0.f;
    float den = w;
    #pragma unroll
    for (int off = 16; off; off >>= 1) den += __shfl_xor(den, off);
    const float ws0 = __expf(e0 - m);
    const float inv = 1.0f / (den + ws0 + 1e-16f);
    const float wl = w * inv;
    {
      float f[CH]; gload<NC>(hb + (size_t)v*C, hl, f);
      const float w0 = ws0 * inv;
      #pragma unroll
      for (int c = 0; c < CH; ++c) acc[c] = w0 * f[c];
    }
    int j = 0;
    for (; j + 8 <= dg; j += 8){
      int ssrc[8]; float ww[8];
      #pragma unroll
      for (int q = 0; q < 8; ++q){
        ssrc[q] = __shfl(srcl, base+j+q);
        ww[q]   = __shfl(wl,   base+j+q);
      }
      float f[8][CH];
      #pragma unroll
      for (int q = 0; q < 8; ++q) gload<NC>(hb + (size_t)ssrc[q]*C, hl, f[q]);
      #pragma unroll
      for (int q = 0; q < 8; ++q)
        #pragma unroll
        for (int c = 0; c < CH; ++c) acc[c] += ww[q]*f[q][c];
    }
    for (; j + 4 <= dg; j += 4){
      int  s0 = __shfl(srcl, base+j),   s1 = __shfl(srcl, base+j+1);
      int  s2 = __shfl(srcl, base+j+2), s3 = __shfl(srcl, base+j+3);
      float w0_ = __shfl(wl, base+j),   w1_ = __shfl(wl, base+j+1);
      float w2_ = __shfl(wl, base+j+2), w3_ = __shfl(wl, base+j+3);
      float f0[CH], f1[CH], f2[CH], f3[CH];
      gload<NC>(hb + (size_t)s0*C, hl, f0);
      gload<NC>(hb + (size_t)s1*C, hl, f1);
      gload<NC>(hb + (size_t)s2*C, hl, f2);
      gload<NC>(hb + (size_t)s3*C, hl, f3);
      #pragma unroll
      for (int c = 0; c < CH; ++c)
        acc[c] += w0_*f0[c] + w1_*f1[c] + w2_*f2[c] + w3_*f3[c];
    }
    for (; j < dg; ++j){
      int src = __shfl(srcl, base+j);
      float w_ = __shfl(wl, base+j);
      float f[CH]; gload<NC>(hb + (size_t)src*C, hl, f);
      #pragma unroll
      for (int c = 0; c < CH; ++c) acc[c] += w_*f[c];
    }
  } else {
    // chunked path (dg>32, rare): spill scores to ew
    float m = e0;
    for (int b0 = 0; b0 < dg; b0 += 32){
      int i = b0 + hl; float sc = -1e30f;
      if (i < dg){ int src = csr[beg + i]; sc = leakyf(s[src] + dv); ew[beg + i] = sc; }
      #pragma unroll
      for (int off = 16; off; off >>= 1) sc = fmaxf(sc, __shfl_xor(sc, off));
      m = fmaxf(m, sc);
    }
    float dsum = 0.f;
    for (int b0 = 0; b0 < dg; b0 += 32){
      int i = b0 + hl; float w = 0.f;
      if (i < dg){ w = __expf(ew[beg + i] - m); ew[beg + i] = w; }
      float cs = w;
      #pragma unroll
      for (int off = 16; off; off >>= 1) cs += __shfl_xor(cs, off);
      dsum += cs;
    }
    const float ws0 = __expf(e0 - m);
    const float inv = 1.0f / (dsum + ws0 + 1e-16f);
    {
      float f[CH]; gload<NC>(hb + (size_t)v*C, hl, f);
      const float w0 = ws0 * inv;
      #pragma unroll
      for (int c = 0; c < CH; ++c) acc[c] = w0 * f[c];
    }
    for (int b0 = 0; b0 < dg; b0 += 32){
      int i = b0 + hl;
      int srcl = 0; float wl = 0.f;
      if (i < dg){ srcl = csr[beg + i]; wl = ew[beg + i] * inv; }
      int cnt = min(32, dg - b0);
      for (int j = 0; j < cnt; ++j){
        int src = __shfl(srcl, base+j);
        float w_ = __shfl(wl, base+j);
        float f[CH]; gload<NC>(hb + (size_t)src*C, hl, f);
        #pragma unroll
        for (int c = 0; c < CH; ++c) acc[c] += w_*f[c];
      }
    }
  }

  // epilogue: bias+relu (BR), pack+store, fused next-layer scores (SDF)
  float vout[CH];
  #pragma unroll
  for (int c = 0; c < CH; ++c){
    float val = acc[c];
    if constexpr (BR) val = reluf(val + bias[CH*hl + c]);
    vout[c] = val;
  }
  unsigned short* op = outp + (size_t)v*C;
  if constexpr (NC == 1){
    ((uint32_t*)op)[hl] = pack2(vout[0], vout[1]);
  } else {
    uint2 u; u.x = pack2(vout[0], vout[1]); u.y = pack2(vout[2], vout[3]);
    ((uint2*)op)[hl] = u;
  }
  if constexpr (SDF){
    float ss = 0.f, dd = 0.f;
    #pragma unroll
    for (int c = 0; c < CH; ++c){
      ss += vout[c] * sdw_s[CH*hl + c];
      dd += vout[c] * sdw_d[CH*hl + c];
    }
    #pragma unroll
    for (int off = 16; off; off >>= 1){ ss += __shfl_xor(ss, off); dd += __shfl_xor(dd, off); }
    if (hl == 0){ s_out[v] = ss; d_out[v] = dd; }
  }
}

// ================= MFMA bf16 GEMM: C = A[MxK] @ W[KxN] (+bias)(+relu) =================
template<int ABF, int OBF>
__global__ __launch_bounds__(256) void gemm_mfma(
    const void* __restrict__ Av, const float* __restrict__ W,
    const float* __restrict__ bias, void* __restrict__ Cv,
    int M, int K, int Kw, int N, int act){
  __shared__ short As[64][40];
  __shared__ short Bs[64][40];
  const int t = threadIdx.x;
  const int row0 = blockIdx.x * 64;
  const int col0 = blockIdx.y * 64;
  const int wv = t >> 6, lane = t & 63;
  const int wr = wv >> 1, wc = wv & 1;
  const int lr = lane & 15, lg = lane >> 4;

  f32x4 acc00 = {}, acc01 = {}, acc10 = {}, acc11 = {};

  for (int k0 = 0; k0 < K; k0 += 32){
    {
      int m = t >> 2, kq = (t & 3) * 8;
      int gr = row0 + m;
      short8 av;
      if constexpr (ABF == 1){
        const unsigned short* Au = (const unsigned short*)Av;
        if (gr < M && (k0 + kq + 7) < K){
          av = *(const short8*)&Au[(size_t)gr*K + k0 + kq];
        } else {
          #pragma unroll
          for (int j = 0; j < 8; ++j){
            int gk = k0 + kq + j;
            av[j] = (gr < M && gk < K) ? (short)Au[(size_t)gr*K + gk] : (short)0;
          }
        }
      } else {
        const float* Af = (const float*)Av;
        if (gr < M && (K % 4) == 0 && (k0 + kq + 7) < K){
          const float4 f0 = *(const float4*)&Af[(size_t)gr*K + k0 + kq];
          const float4 f1 = *(const float4*)&Af[(size_t)gr*K + k0 + kq + 4];
          av[0]=f2bf(f0.x); av[1]=f2bf(f0.y); av[2]=f2bf(f0.z); av[3]=f2bf(f0.w);
          av[4]=f2bf(f1.x); av[5]=f2bf(f1.y); av[6]=f2bf(f1.z); av[7]=f2bf(f1.w);
        } else {
          #pragma unroll
          for (int j = 0; j < 8; ++j){
            int gk = k0 + kq + j;
            float val = (gr < M && gk < K) ? Af[(size_t)gr*K + gk] : 0.f;
            av[j] = f2bf(val);
          }
        }
      }
      *(short8*)&As[m][kq] = av;
    }
    {
      int n = t & 63, k8 = (t >> 6) * 8;
      short8 bv;
      #pragma unroll
      for (int j = 0; j < 8; ++j){
        int gk = k0 + k8 + j;
        float val = (gk < Kw) ? W[(size_t)gk*N + col0 + n] : 0.f;
        bv[j] = f2bf(val);
      }
      *(short8*)&Bs[n][k8] = bv;
    }
    __syncthreads();
    short8 af0 = *(short8*)&As[wr*32 +  0 + lr][lg*8];
    short8 af1 = *(short8*)&As[wr*32 + 16 + lr][lg*8];
    short8 bf0 = *(short8*)&Bs[wc*32 +  0 + lr][lg*8];
    short8 bf1 = *(short8*)&Bs[wc*32 + 16 + lr][lg*8];
    acc00 = __builtin_amdgcn_mfma_f32_16x16x32_bf16(af0, bf0, acc00, 0, 0, 0);
    acc01 = __builtin_amdgcn_mfma_f32_16x16x32_bf16(af0, bf1, acc01, 0, 0, 0);
    acc10 = __builtin_amdgcn_mfma_f32_16x16x32_bf16(af1, bf0, acc10, 0, 0, 0);
    acc11 = __builtin_amdgcn_mfma_f32_16x16x32_bf16(af1, bf1, acc11, 0, 0, 0);
    __syncthreads();
  }

  #pragma unroll
  for (int fm = 0; fm < 2; ++fm){
    #pragma unroll
    for (int fn = 0; fn < 2; ++fn){
      const f32x4 a = (fm==0) ? (fn==0 ? acc00 : acc01) : (fn==0 ? acc10 : acc11);
      int col = col0 + wc*32 + fn*16 + lr;
      float bv = bias ? bias[col] : 0.f;
      #pragma unroll
      for (int j = 0; j < 4; ++j){
        int row = row0 + wr*32 + fm*16 + lg*4 + j;
        if (row >= M) continue;
        float val = a[j] + bv;
        if (act) val = reluf(val);
        if constexpr (OBF == 0) ((float*)Cv)[(size_t)row*N + col] = val;
        else ((unsigned short*)Cv)[(size_t)row*N + col] = f2bf(val);
      }
    }
  }
}

// ================= fused policy tail2: p1[N,128]bf16 -> 64 -> 32 -> 1 =================
// One node per thread. Weights are wave-uniform -> scalar (s_load) broadcasts.
__global__ __launch_bounds__(256) void policy_tail2_kernel(
    const unsigned short* __restrict__ p1,
    const float* __restrict__ W1, const float* __restrict__ B1,   // [128,64],[64]
    const float* __restrict__ W2, const float* __restrict__ B2,   // [64,32],[32]
    const float* __restrict__ W3, const float* __restrict__ B3,   // [32],[1]
    float* __restrict__ out, int n){
  int v = blockIdx.x*256 + threadIdx.x;
  if (v >= n) return;
  const uint32_t* row = (const uint32_t*)(p1 + (size_t)v*128);
  float acc[64];
  #pragma unroll
  for (int o = 0; o < 64; ++o) acc[o] = B1[o];
  for (int k2 = 0; k2 < 64; ++k2){          // 2 bf16 per uint32
    uint32_t u = row[k2];
    float x0 = bf2f((unsigned short)(u & 0xFFFFu));
    float x1 = bf2f((unsigned short)(u >> 16));
    const float* w0p = W1 + (size_t)(2*k2)*64;
    const float* w1p = W1 + (size_t)(2*k2 + 1)*64;
    #pragma unroll
    for (int o = 0; o < 64; ++o) acc[o] += x0*w0p[o] + x1*w1p[o];
  }
  float acc2[32];
  #pragma unroll
  for (int o = 0; o < 32; ++o) acc2[o] = B2[o];
  #pragma unroll 4
  for (int k = 0; k < 64; ++k){
    float xk = reluf(acc[k]);
    #pragma unroll
    for (int o = 0; o < 32; ++o) acc2[o] += xk * W2[k*32 + o];
  }
  float accf = B3[0];
  #pragma unroll
  for (int o = 0; o < 32; ++o) accf += reluf(acc2[o]) * W3[o];
  out[v] = accf;
}

// ================= graph boundaries =================
__global__ void bounds_kernel(const int* __restrict__ batch, int* __restrict__ gstart,
                              int n, int G){
  int g = threadIdx.x;
  if (g > G) return;
  int lo = 0, hi = n;
  while (lo < hi){ int mid = (lo + hi) >> 1; if (batch[mid] < g) lo = mid + 1; else hi = mid; }
  gstart[g] = lo;
}

// ================= global add pool: 2-stage split reduction =================
__global__ __launch_bounds__(128) void pool_split_kernel(const float* __restrict__ x,
    const int* __restrict__ gstart, float* __restrict__ partial){
  int g = blockIdx.x, sp = blockIdx.y, f = threadIdx.x;
  int beg = gstart[g], end = gstart[g+1];
  int len = end - beg;
  int chunk = (len + POOL_SPLIT - 1) / POOL_SPLIT;
  int lo = beg + sp*chunk;
  int hi = min(lo + chunk, end);
  float acc = 0.f;
  for (int r = lo; r < hi; ++r) acc += x[(size_t)r*128 + f];
  partial[((size_t)g*POOL_SPLIT + sp)*128 + f] = acc;
}
__global__ __launch_bounds__(128) void pool_final_kernel(const float* __restrict__ partial,
    float* __restrict__ pooled){
  int g = blockIdx.x, f = threadIdx.x;
  float acc = 0.f;
  #pragma unroll
  for (int sp = 0; sp < POOL_SPLIT; ++sp)
    acc += partial[((size_t)g*POOL_SPLIT + sp)*128 + f];
  pooled[g*128 + f] = acc;
}

// ================= value MLP =================
__global__ __launch_bounds__(128) void value_mlp_kernel(const float* __restrict__ pooled,
    const float* __restrict__ W0, const float* __restrict__ B0,
    const float* __restrict__ W1, const float* __restrict__ B1,
    const float* __restrict__ W2, const float* __restrict__ B2,
    const float* __restrict__ W3, const float* __restrict__ B3,
    float* __restrict__ outv){
  __shared__ float a[128], b[128];
  int g = blockIdx.x, t = threadIdx.x;
  a[t] = pooled[g*128 + t];
  __syncthreads();
  float acc = B0[t];
  for (int k = 0; k < 128; ++k) acc += a[k]*W0[k*128 + t];
  b[t] = reluf(acc);
  __syncthreads();
  if (t < 64){ acc = B1[t]; for (int k = 0; k < 128; ++k) acc += b[k]*W1[k*64 + t]; a[t] = reluf(acc); }
  __syncthreads();
  if (t < 32){ acc = B2[t]; for (int k = 0; k < 64; ++k) acc += a[k]*W2[k*32 + t]; b[t] = reluf(acc); }
  __syncthreads();
  if (t == 0){ acc = B3[0]; for (int k = 0; k < 32; ++k) acc += b[k]*W3[k]; outv[g] = acc; }
}

extern "C" void kernel_launch(void* const* d_in, const int* in_sizes, int n_in,
                              void* d_out, int out_size, void* d_ws, size_t ws_size,
                              hipStream_t stream){
  const float* x     = (const float*)d_in[0];
  const int*   ei    = (const int*)d_in[1];
  const int*   batch = (const int*)d_in[2];
  const float* W1 = (const float*)d_in[3];
  const float* as1= (const float*)d_in[4];
  const float* ad1= (const float*)d_in[5];
  const float* b1 = (const float*)d_in[6];
  const float* W2 = (const float*)d_in[7];
  const float* as2= (const float*)d_in[8];
  const float* ad2= (const float*)d_in[9];
  const float* b2 = (const float*)d_in[10];
  const float* W3 = (const float*)d_in[11];
  const float* as3= (const float*)d_in[12];
  const float* ad3= (const float*)d_in[13];
  const float* b3 = (const float*)d_in[14];
  const float* pW0= (const float*)d_in[15];
  const float* pb0= (const float*)d_in[16];
  const float* pW1= (const float*)d_in[17];
  const float* pb1= (const float*)d_in[18];
  const float* pW2= (const float*)d_in[19];
  const float* pb2= (const float*)d_in[20];
  const float* pW3= (const float*)d_in[21];
  const float* pb3= (const float*)d_in[22];
  const float* vW0= (const float*)d_in[23];
  const float* vb0= (const float*)d_in[24];
  const float* vW1= (const float*)d_in[25];
  const float* vb1= (const float*)d_in[26];
  const float* vW2= (const float*)d_in[27];
  const float* vb2= (const float*)d_in[28];
  const float* vW3= (const float*)d_in[29];
  const float* vb3= (const float*)d_in[30];
  float* out = (float*)d_out;

  // -------- workspace carve --------
  char* ws = (char*)d_ws;
  size_t off = 0;
  auto carve = [&](size_t bytes)->char*{
    char* p = ws + off; off = (off + bytes + 255) & ~(size_t)255; return p;
  };
  int*   deg    = (int*)  carve((size_t)N_NODES*4);
  int*   rowptr = (int*)  carve((size_t)(N_NODES+1)*4);
  int*   pos    = (int*)  carve((size_t)N_EDGES*4);
  int*   csr    = (int*)  carve((size_t)N_EDGES*4);
  int*   bsum   = (int*)  carve(512*4);
  float* ew     = (float*)carve((size_t)N_EDGES*4);
  float* s      = (float*)carve((size_t)N_NODES*4);
  float* dsc    = (float*)carve((size_t)N_NODES*4);
  float* s2     = (float*)carve((size_t)N_NODES*4);
  float* d2     = (float*)carve((size_t)N_NODES*4);
  float* wa     = (float*)carve(1024*4);
  int*   gstart = (int*)  carve(65*4);
  float* pooled = (float*)carve((size_t)N_GRAPHS*128*4);
  float* partial= (float*)carve((size_t)N_GRAPHS*POOL_SPLIT*128*4);
  uint32_t*       xb   = (uint32_t*)      carve((size_t)N_NODES*64*2);   // bf16 [N,64] padded
  unsigned short* aggx = (unsigned short*)carve((size_t)N_NODES*64*2);   // bf16 [N,64]
  unsigned short* out1 = (unsigned short*)carve((size_t)N_NODES*256*2);  // bf16 [N,256]
  unsigned short* h2   = (unsigned short*)carve((size_t)N_NODES*128*2);  // bf16 [N,128]
  unsigned short* out2 = (unsigned short*)carve((size_t)N_NODES*128*2);  // bf16 [N,128]
  unsigned short* agg3 = (unsigned short*)carve((size_t)N_NODES*128*2);  // bf16 [N,128]
  float* out3 = (float*)carve((size_t)N_NODES*128*4);                    // f32 [N,128]
  // reuse dead region for policy MLP intermediate
  unsigned short* p1 = h2;          // bf16 [N,128] — h2 dead after agg2

  const int* esrc = ei;              // edge_index[0]
  const int* edst = ei + N_EDGES;    // edge_index[1]

  const int NBn  = (N_NODES + 255)/256;
  const int NBe  = (N_EDGES + 255)/256;
  const int GB   = (N_NODES + 63) / 64;   // 1563
  const int NB4  = (N_NODES + 3) / 4;
  const int NB8  = (N_NODES + 7) / 8;

  // -------- prep: wa, CSR build, x->bf16+sd1, bounds --------
  wa_all_kernel<<<1, 256, 0, stream>>>(W1, as1, ad1, W2, as2, ad2, W3, as3, ad3, wa);
  zero_deg_kernel<<<NBn, 256, 0, stream>>>(deg, N_NODES);
  count_kernel<<<NBe, 256, 0, stream>>>(edst, deg, pos, N_EDGES);
  scan1_kernel<<<NBn, 256, 0, stream>>>(deg, rowptr, bsum, N_NODES);
  scan2_kernel<<<1, 512, 0, stream>>>(bsum, NBn);
  scan3_kernel<<<NBn, 256, 0, stream>>>(rowptr, bsum, N_NODES);
  scatter_kernel<<<NBe, 256, 0, stream>>>(esrc, edst, rowptr, pos, csr, N_EDGES);
  x2bf_sd_kernel<<<NB8, 256, 0, stream>>>(x, wa+0, wa+64, xb, s, dsc, N_NODES);
  bounds_kernel<<<1, 128, 0, stream>>>(batch, gstart, N_NODES, N_GRAPHS);

  // ---- layer 1 (pre-agg): agg(xb) -> GEMM(+b1,relu) -> out1 bf16
  agg_half<1,0,0><<<NB8, 256, 0, stream>>>((const unsigned short*)xb, s, dsc, rowptr, deg, csr, ew,
                                           nullptr, nullptr, nullptr, nullptr, nullptr,
                                           aggx, N_NODES);
  gemm_mfma<1,1><<<dim3(GB,4), 256, 0, stream>>>(aggx, W1, b1, out1, N_NODES, 64, 59, 256, 1);

  // ---- layer 2 (post-agg): sd(out1) -> GEMM -> h2 -> agg(+b2,relu, fused sd3->s2/d2) -> out2
  sd_bf16_kernel<<<NB4, 256, 0, stream>>>(out1, wa+128, wa+384, s, dsc, N_NODES, 256);
  gemm_mfma<1,1><<<dim3(GB,2), 256, 0, stream>>>(out1, W2, nullptr, h2, N_NODES, 256, 256, 128, 0);
  agg_half<2,1,1><<<NB8, 256, 0, stream>>>(h2, s, dsc, rowptr, deg, csr, ew,
                                           b2, wa+640, wa+768, s2, d2, out2, N_NODES);

  // ---- layer 3 (pre-agg): agg(out2, scores s2/d2) -> GEMM(+b3,relu) -> out3 f32
  agg_half<2,0,0><<<NB8, 256, 0, stream>>>(out2, s2, d2, rowptr, deg, csr, ew,
                                           nullptr, nullptr, nullptr, nullptr, nullptr,
                                           agg3, N_NODES);
  gemm_mfma<1,0><<<dim3(GB,2), 256, 0, stream>>>(agg3, W3, b3, out3, N_NODES, 128, 128, 128, 1);

  // ---- policy MLP: out3 -> p1(bf16) -> fused 128->64->32->1 -> out[0..N)
  gemm_mfma<0,1><<<dim3(GB,2), 256, 0, stream>>>(out3, pW0, pb0, p1, N_NODES, 128, 128, 128, 1);
  policy_tail2_kernel<<<NBn, 256, 0, stream>>>(p1, pW1, pb1, pW2, pb2, pW3, pb3, out, N_NODES);

  // ---- pool + value MLP -> out[N..N+64)
  pool_split_kernel<<<dim3(N_GRAPHS, POOL_SPLIT), 128, 0, stream>>>(out3, gstart, partial);
  pool_final_kernel<<<N_GRAPHS, 128, 0, stream>>>(partial, pooled);
  value_mlp_kernel<<<N_GRAPHS, 128, 0, stream>>>(pooled, vW0, vb0, vW1, vb1, vW2, vb2, vW3, vb3,
                                                 out + N_NODES);
}